// Round 12
// baseline (220.289 us; speedup 1.0000x reference)
//
#include <hip/hip_runtime.h>
#include <math.h>

#define N_NODES 100000
#define N_EDGES 1000000
#define IN_DIM  128
#define OUT_DIM 64
#define NEG     0.2f

#define SCAN_BLOCKS 391   // ceil(100000/256)
#define FILL_BLOCKS 977   // ceil(1000000/1024): 4 edges/thread

// histogram decomposition: 80 edge-groups x 4 node-chunks
#define G_GROUPS 80
#define EPG      (N_EDGES / G_GROUPS)   // 12500 edges per group (even)
#define NI2      (EPG / 2)              // 6250 int2 per group
#define CHUNK_N  25000                  // nodes per chunk (50 KB packed u16)
#define HIST_BLOCKS (G_GROUPS * 4)      // 320

// ---------------------------------------------------------------------------
// K1: Wh = h@W^T + b via bf16x2 split-precision MFMA. Wh stored as RNE bf16
// (Whb). Scores fp32. (unchanged — R5-proven)
// ---------------------------------------------------------------------------
typedef __attribute__((ext_vector_type(8))) short short8;   // 8 bf16 = 4 VGPR
typedef __attribute__((ext_vector_type(4))) float f32x4;

#define MFMA(A, B, C) __builtin_amdgcn_mfma_f32_16x16x32_bf16(A, B, C, 0, 0, 0)

union U16 { unsigned u[4]; short8 s; };

__device__ __forceinline__ void split8(const float* x, short8& hi, short8& lo) {
    U16 H, L;
#pragma unroll
    for (int i = 0; i < 4; ++i) {
        float a = x[2 * i], b = x[2 * i + 1];
        unsigned ua = __float_as_uint(a), ub = __float_as_uint(b);
        unsigned ha = ua & 0xffff0000u, hb = ub & 0xffff0000u;
        H.u[i] = (ua >> 16) | hb;
        float la = a - __uint_as_float(ha);     // exact (low mantissa bits)
        float lb = b - __uint_as_float(hb);
        L.u[i] = (__float_as_uint(la) >> 16) | (__float_as_uint(lb) & 0xffff0000u);
    }
    hi = H.s; lo = L.s;
}

// pack two fp32 -> one u32 of two RNE bf16
__device__ __forceinline__ unsigned pk2(float a, float b) {
    unsigned ua = __float_as_uint(a); ua = (ua + 0x7fffu + ((ua >> 16) & 1u)) >> 16;
    unsigned ub = __float_as_uint(b); ub = (ub + 0x7fffu + ((ub >> 16) & 1u)) >> 16;
    return ua | (ub << 16);
}

__global__ __launch_bounds__(256, 3) void k1_mfma(
    const float* __restrict__ h, const float* __restrict__ W,
    const float* __restrict__ Wb, const float* __restrict__ aw,
    unsigned short* __restrict__ Whb, float* __restrict__ s_src,
    float* __restrict__ s_tgt)
{
    __shared__ float4 smem4[2176];     // 34816 B: W frags, then tr[128][68]
    unsigned short* wfh = (unsigned short*)smem4;
    unsigned short* wfl = wfh + 8192;

    const int tid  = threadIdx.x;
    const int lane = tid & 63, w = tid >> 6;
    const int c = lane & 15, g = lane >> 4;
    const int n0 = blockIdx.x * 128;

#pragma unroll
    for (int it = 0; it < 4; ++it) {
        int U = tid + 256 * it;                 // 0..1023
        int pos = U >> 6, l = U & 63;
        int nb = pos >> 2, ks = pos & 3;
        int r  = 16 * nb + (l & 15);
        int k0 = 32 * ks + 8 * (l >> 4);
        float a[8];
        *(float4*)&a[0] = *(const float4*)(W + r * IN_DIM + k0);
        *(float4*)&a[4] = *(const float4*)(W + r * IN_DIM + k0 + 4);
        short8 hi, lo; split8(a, hi, lo);
        *(short8*)(wfh + (size_t)U * 8) = hi;   // stride-1 b128 writes
        *(short8*)(wfl + (size_t)U * 8) = lo;
    }
    __syncthreads();

    const int na0 = n0 + 32 * w + c;
    const float* hp0 = h + (size_t)min(na0, N_NODES - 1) * IN_DIM + 8 * g;
    const float* hp1 = h + (size_t)min(na0 + 16, N_NODES - 1) * IN_DIM + 8 * g;

    f32x4 acc[2][4];
    {
        f32x4 z = {0.f, 0.f, 0.f, 0.f};
#pragma unroll
        for (int m = 0; m < 2; ++m)
#pragma unroll
            for (int nb = 0; nb < 4; ++nb) acc[m][nb] = z;
    }

#pragma unroll 2
    for (int ks = 0; ks < 4; ++ks) {
        short8 bh[4], bl[4];
#pragma unroll
        for (int nb = 0; nb < 4; ++nb) {
            int u = ((nb * 4 + ks) * 64 + lane) * 8;
            bh[nb] = *(const short8*)(wfh + u);
            bl[nb] = *(const short8*)(wfl + u);
        }
        float am[8];
        short8 ah, al;
        *(float4*)&am[0] = *(const float4*)(hp0 + 32 * ks);
        *(float4*)&am[4] = *(const float4*)(hp0 + 32 * ks + 4);
        split8(am, ah, al);
#pragma unroll
        for (int nb = 0; nb < 4; ++nb) {
            acc[0][nb] = MFMA(ah, bh[nb], acc[0][nb]);
            acc[0][nb] = MFMA(ah, bl[nb], acc[0][nb]);
            acc[0][nb] = MFMA(al, bh[nb], acc[0][nb]);
        }
        *(float4*)&am[0] = *(const float4*)(hp1 + 32 * ks);
        *(float4*)&am[4] = *(const float4*)(hp1 + 32 * ks + 4);
        split8(am, ah, al);
#pragma unroll
        for (int nb = 0; nb < 4; ++nb) {
            acc[1][nb] = MFMA(ah, bh[nb], acc[1][nb]);
            acc[1][nb] = MFMA(ah, bl[nb], acc[1][nb]);
            acc[1][nb] = MFMA(al, bh[nb], acc[1][nb]);
        }
    }

    // epilogue: bias + score dot-products (fp32, pre-cast).
    // D-frag: lane holds Wh[32w + 16m + 4g + r][16nb + c], r = 0..3.
    float wb[4], w1[4], w2[4];
#pragma unroll
    for (int nb = 0; nb < 4; ++nb) {
        wb[nb] = Wb[16 * nb + c];
        w1[nb] = aw[16 * nb + c];
        w2[nb] = aw[OUT_DIM + 16 * nb + c];
    }
#pragma unroll
    for (int m = 0; m < 2; ++m)
#pragma unroll
        for (int r = 0; r < 4; ++r) {
            float s1 = 0.f, s2 = 0.f;
#pragma unroll
            for (int nb = 0; nb < 4; ++nb) {
                float v = acc[m][nb][r] + wb[nb];
                acc[m][nb][r] = v;
                s1 = fmaf(v, w1[nb], s1);
                s2 = fmaf(v, w2[nb], s2);
            }
#pragma unroll
            for (int mk = 1; mk < 16; mk <<= 1) {
                s1 += __shfl_xor(s1, mk);
                s2 += __shfl_xor(s2, mk);
            }
            if (c == 0) {
                int node = n0 + 32 * w + 16 * m + 4 * g + r;
                if (node < N_NODES) { s_src[node] = s1; s_tgt[node] = s2; }
            }
        }

    __syncthreads();                 // all LDS W reads done; reuse as tr
    float* tr = (float*)smem4;       // tr[128][68]
#pragma unroll
    for (int m = 0; m < 2; ++m)
#pragma unroll
        for (int nb = 0; nb < 4; ++nb)
#pragma unroll
            for (int r = 0; r < 4; ++r)
                tr[(32 * w + 16 * m + 4 * g + r) * 68 + 16 * nb + c] = acc[m][nb][r];
    __syncthreads();

    // coalesced Whb store: 1024 uint4 (8 bf16 each), 4 per thread
#pragma unroll
    for (int j = 0; j < 4; ++j) {
        int idx = tid + 256 * j;              // 0..1023
        int nloc = idx >> 3, q = idx & 7;
        int node = n0 + nloc;
        if (node < N_NODES) {
            const float* r8 = &tr[nloc * 68 + q * 8];
            uint4 u;
            u.x = pk2(r8[0], r8[1]); u.y = pk2(r8[2], r8[3]);
            u.z = pk2(r8[4], r8[5]); u.w = pk2(r8[6], r8[7]);
            ((uint4*)Whb)[(size_t)node * 8 + q] = u;
        }
    }
}

// ---------------------------------------------------------------------------
// k_hist: packed-u16 LDS counters, 320 blocks, 8-deep load batch.
// (unchanged — R10-proven)
// ---------------------------------------------------------------------------
__global__ __launch_bounds__(256) void k_hist(
    const int* __restrict__ ei, unsigned char* __restrict__ deg_g8,
    unsigned* __restrict__ rank)
{
    __shared__ unsigned cnt[CHUNK_N / 2];      // 50 KB, two u16 per word
    const int g  = blockIdx.x >> 2;
    const int c0 = (blockIdx.x & 3) * CHUNK_N;
    const int tid = threadIdx.x;

    for (int i = tid; i < CHUNK_N / 2; i += 256) cnt[i] = 0u;
    __syncthreads();

    const int ebase = g * EPG;
    const int2* tp2 = (const int2*)(ei + N_EDGES + ebase);
    for (int b = 0; b < 32; b += 8) {
        int2 tv[8];
#pragma unroll
        for (int k = 0; k < 8; ++k) {
            int idx = tid + (b + k) * 256;
            tv[k] = (idx < NI2) ? tp2[idx] : make_int2(-0x40000000, -0x40000000);
        }
#pragma unroll
        for (int k = 0; k < 8; ++k) {
            int idx = tid + (b + k) * 256;
            int e0 = ebase + 2 * idx;
            unsigned u0 = (unsigned)(tv[k].x - c0), u1 = (unsigned)(tv[k].y - c0);
            if (u0 < CHUNK_N) {
                unsigned sh = (u0 & 1u) * 16u;
                unsigned old = atomicAdd(&cnt[u0 >> 1], 1u << sh);
                rank[e0] = (old >> sh) & 0xffffu;
            }
            if (u1 < CHUNK_N) {
                unsigned sh = (u1 & 1u) * 16u;
                unsigned old = atomicAdd(&cnt[u1 >> 1], 1u << sh);
                rank[e0 + 1] = (old >> sh) & 0xffffu;
            }
        }
    }
    __syncthreads();

    unsigned* dg = (unsigned*)(deg_g8 + (size_t)g * N_NODES + c0);
    for (int i = tid; i < CHUNK_N / 4; i += 256) {
        unsigned w0 = cnt[2 * i], w1 = cnt[2 * i + 1];
        dg[i] = (w0 & 0xffu) | (((w0 >> 16) & 0xffu) << 8) |
                ((w1 & 0xffu) << 16) | (((w1 >> 16) & 0xffu) << 24);
    }
}

// ---------------------------------------------------------------------------
// k_scanA: psum[b] = total degree of node block b. (unchanged)
// ---------------------------------------------------------------------------
__global__ __launch_bounds__(256) void k_scanA(
    const unsigned char* __restrict__ deg_g8, unsigned* __restrict__ psum)
{
    const int i = blockIdx.x * 256 + threadIdx.x;
    unsigned v = 0;
    if (i < N_NODES) {
#pragma unroll
        for (int x = 0; x < G_GROUPS; ++x)
            v += deg_g8[(size_t)x * N_NODES + i];
    }
#pragma unroll
    for (int off = 32; off; off >>= 1) v += __shfl_xor(v, off);
    __shared__ unsigned us[4];
    if ((threadIdx.x & 63) == 0) us[threadIdx.x >> 6] = v;
    __syncthreads();
    if (threadIdx.x == 0) psum[blockIdx.x] = us[0] + us[1] + us[2] + us[3];
}

// ---------------------------------------------------------------------------
// k_scan3: row[] (CSR) + per-group relative u8 offsets roff[g][t].
// (unchanged — R11-proven)
// ---------------------------------------------------------------------------
__global__ __launch_bounds__(256) void k_scan3(
    const unsigned char* __restrict__ deg_g8, const unsigned* __restrict__ psum,
    unsigned* __restrict__ row, unsigned char* __restrict__ roff)
{
    __shared__ unsigned sc[256];
    __shared__ unsigned ps[4];
    const int t = threadIdx.x;
    const int i = blockIdx.x * 256 + t;

    // block base = sum of psum[0 .. blockIdx.x-1]
    unsigned pv = 0;
    if (t < blockIdx.x) pv = psum[t];
    if (t + 256 < blockIdx.x) pv += psum[t + 256];
#pragma unroll
    for (int off = 32; off; off >>= 1) pv += __shfl_xor(pv, off);
    if ((t & 63) == 0) ps[t >> 6] = pv;

    unsigned tot = 0;
    if (i < N_NODES) {
#pragma unroll
        for (int x = 0; x < G_GROUPS; ++x)
            tot += deg_g8[(size_t)x * N_NODES + i];
    }
    sc[t] = tot;
    __syncthreads();
    for (int off = 1; off < 256; off <<= 1) {
        unsigned u = (t >= off) ? sc[t - off] : 0u;
        __syncthreads();
        sc[t] += u;
        __syncthreads();
    }
    const unsigned bb = ps[0] + ps[1] + ps[2] + ps[3];
    if (i < N_NODES) {
        row[i] = bb + sc[t] - tot;          // exclusive
        unsigned run = 0;                    // relative prefix, fits u8
#pragma unroll
        for (int x = 0; x < G_GROUPS; ++x) {
            roff[(size_t)x * N_NODES + i] = (unsigned char)run;
            run += deg_g8[(size_t)x * N_NODES + i];
        }
    }
    if (i == 0) row[N_NODES] = N_EDGES;
}

// ---------------------------------------------------------------------------
// k_fill: 4 edges/thread, batched gather chains. (unchanged — R11-proven)
// ---------------------------------------------------------------------------
__global__ __launch_bounds__(256) void k_fill(
    const int* __restrict__ ei, const float* __restrict__ s_src,
    const float* __restrict__ s_tgt, const float* __restrict__ ab,
    const unsigned* __restrict__ rank, const unsigned* __restrict__ row,
    const unsigned char* __restrict__ roff,
    int2* __restrict__ bin, float* __restrict__ bsum)
{
    const float ab0 = ab[0];
    const int base = blockIdx.x * 1024 + threadIdx.x;

    int  s[4], t[4], ee[4];
    bool ok[4];
#pragma unroll
    for (int k = 0; k < 4; ++k) {
        int e = base + 256 * k;
        ok[k] = e < N_EDGES;
        ee[k] = ok[k] ? e : 0;
        s[k] = ei[ee[k]];
        t[k] = ei[N_EDGES + ee[k]];
    }

    float xs[4], xt[4];
    unsigned ps_[4], rk[4];
#pragma unroll
    for (int k = 0; k < 4; ++k) {
        xs[k] = s_src[s[k]];
        xt[k] = s_tgt[t[k]];
        int g = ee[k] / EPG;                  // const div -> magic multiply
        ps_[k] = row[t[k]] + roff[(size_t)g * N_NODES + t[k]];
        rk[k] = rank[ee[k]];
    }

    float lsum = 0.f;
#pragma unroll
    for (int k = 0; k < 4; ++k) {
        float x = xs[k] + xt[k] + ab0;
        float l = x > 0.f ? x : NEG * x;
        float ex = __expf(l);
        if (ok[k]) {
            lsum += ex;
            bin[ps_[k] + rk[k]] = make_int2(s[k], __float_as_int(ex));
        }
    }
#pragma unroll
    for (int off = 32; off; off >>= 1) lsum += __shfl_xor(lsum, off);
    __shared__ float ssum[4];
    if ((threadIdx.x & 63) == 0) ssum[threadIdx.x >> 6] = lsum;
    __syncthreads();
    if (threadIdx.x == 0)
        bsum[blockIdx.x] = ssum[0] + ssum[1] + ssum[2] + ssum[3];
}

// ---------------------------------------------------------------------------
// K4 (R12): 8 nodes/wave (32 edges in flight; R9's 4-node ILP fix doubled)
// + k_gsum FOLDED IN: each block reduces bsum[977] itself (4 coalesced
// loads/thread + wave reduce, L2-hot, deterministic order -> identical inv
// across blocks). Removes one dispatch. Per-node summation order unchanged
// (padded steps contribute exact +0.0) -> per-node sums bitwise-identical.
// Grid: 100000 / 32 = 3125 blocks exactly.
// ---------------------------------------------------------------------------
__global__ __launch_bounds__(256) void k_gather(
    const unsigned* __restrict__ row, const int2* __restrict__ bin,
    const float* __restrict__ bsum, const unsigned short* __restrict__ Whb,
    float* __restrict__ out)
{
    __shared__ float ssum[4];
    const int tid = threadIdx.x;

    // ---- folded gsum: block-local reduce of bsum[FILL_BLOCKS] ----
    {
        float s = 0.f;
#pragma unroll
        for (int k = 0; k < 4; ++k) {
            int i = tid + 256 * k;
            if (i < FILL_BLOCKS) s += bsum[i];
        }
#pragma unroll
        for (int off = 32; off; off >>= 1) s += __shfl_xor(s, off);
        if ((tid & 63) == 0) ssum[tid >> 6] = s;
    }
    __syncthreads();
    const float inv = 1.0f / (ssum[0] + ssum[1] + ssum[2] + ssum[3]);

    const int lane = tid & 63;
    const int tb = blockIdx.x * 32 + (tid >> 6) * 8;   // 8 nodes/wave
    const int q = lane >> 4, sub = lane & 15;

    unsigned r[9];
#pragma unroll
    for (int n = 0; n < 9; ++n) r[n] = row[tb + n];    // tb+8 <= 100000 ✓
    unsigned bs[8];
#pragma unroll
    for (int n = 0; n < 8; ++n) bs[n] = r[n];

    f32x4 a[8];
#pragma unroll
    for (int n = 0; n < 8; ++n) a[n] = (f32x4){0.f, 0.f, 0.f, 0.f};

    while (true) {
        bool any = false;                               // wave-uniform
#pragma unroll
        for (int n = 0; n < 8; ++n) any = any || (bs[n] < r[n + 1]);
        if (!any) break;

        int  c[8];
        int2 p[8];
#pragma unroll
        for (int n = 0; n < 8; ++n) {
            c[n] = (bs[n] < r[n + 1]) ? (int)min(64u, r[n + 1] - bs[n]) : 0;
            p[n] = make_int2(0, 0);                     // pad: (src 0, w +0.0)
            if (lane < c[n]) p[n] = bin[bs[n] + lane];  // coalesced 8B/lane
        }
        int cm = 0;
#pragma unroll
        for (int n = 0; n < 8; ++n) cm = max(cm, c[n]);

        for (int j = 0; j < cm; j += 4) {
#pragma unroll
            for (int n = 0; n < 8; ++n) {               // 8 independent chains
                int   sN = __shfl(p[n].x, j + q);
                float wN = __int_as_float(__shfl(p[n].y, j + q));
                ushort4 v = *(const ushort4*)(Whb + (size_t)sN * OUT_DIM + 4 * sub);
                a[n].x = fmaf(wN, __uint_as_float((unsigned)v.x << 16), a[n].x);
                a[n].y = fmaf(wN, __uint_as_float((unsigned)v.y << 16), a[n].y);
                a[n].z = fmaf(wN, __uint_as_float((unsigned)v.z << 16), a[n].z);
                a[n].w = fmaf(wN, __uint_as_float((unsigned)v.w << 16), a[n].w);
            }
        }
#pragma unroll
        for (int n = 0; n < 8; ++n) bs[n] += 64;
    }

#pragma unroll
    for (int n = 0; n < 8; ++n) {
        a[n].x += __shfl_xor(a[n].x, 16); a[n].x += __shfl_xor(a[n].x, 32);
        a[n].y += __shfl_xor(a[n].y, 16); a[n].y += __shfl_xor(a[n].y, 32);
        a[n].z += __shfl_xor(a[n].z, 16); a[n].z += __shfl_xor(a[n].z, 32);
        a[n].w += __shfl_xor(a[n].w, 16); a[n].w += __shfl_xor(a[n].w, 32);
        float rr = (q == 0) ? a[n].x : (q == 1) ? a[n].y : (q == 2) ? a[n].z
                                                                   : a[n].w;
        rr *= inv;
        rr = rr > 0.f ? rr : NEG * rr;
        out[(size_t)(tb + n) * OUT_DIM + 4 * sub + q] = rr;
    }
}

extern "C" void kernel_launch(void* const* d_in, const int* in_sizes, int n_in,
                              void* d_out, int out_size, void* d_ws, size_t ws_size,
                              hipStream_t stream)
{
    const float* h  = (const float*)d_in[0];
    const float* W  = (const float*)d_in[1];
    const float* Wb = (const float*)d_in[2];
    const float* aw = (const float*)d_in[3];
    const float* ab = (const float*)d_in[4];
    const int*   ei = (const int*)d_in[5];

    // ws: Whb[64N] u16 (12.8MB) | bin[E] int2 (8-aligned) | s_src[N] f32 |
    //     s_tgt[N] f32 | deg_g8[80N] u8 | row[N+1] u32 | roff[80N] u8 |
    //     psum[512] u32 | rank[E] u32 | bsum[1024] f32        (~43 MB)
    unsigned short* Whb = (unsigned short*)d_ws;
    int2*  bin   = (int2*)(Whb + (size_t)N_NODES * OUT_DIM);   // 12.8M % 8 == 0
    float* s_src = (float*)(bin + N_EDGES);
    float* s_tgt = s_src + N_NODES;
    unsigned char* deg_g8 = (unsigned char*)(s_tgt + N_NODES);
    unsigned* row  = (unsigned*)(deg_g8 + (size_t)G_GROUPS * N_NODES);
    unsigned char* roff = (unsigned char*)(row + N_NODES + 1);
    unsigned* psum = (unsigned*)(roff + (size_t)G_GROUPS * N_NODES);
    unsigned* rank = psum + 512;
    float* bsum = (float*)(rank + N_EDGES);

    float* out = (float*)d_out;

    k_hist<<<HIST_BLOCKS, 256, 0, stream>>>(ei, deg_g8, rank);
    k1_mfma<<<(N_NODES + 127) / 128, 256, 0, stream>>>(h, W, Wb, aw, Whb,
                                                       s_src, s_tgt);
    k_scanA<<<SCAN_BLOCKS, 256, 0, stream>>>(deg_g8, psum);
    k_scan3<<<SCAN_BLOCKS, 256, 0, stream>>>(deg_g8, psum, row, roff);
    k_fill<<<FILL_BLOCKS, 256, 0, stream>>>(ei, s_src, s_tgt, ab, rank,
                                            row, roff, bin, bsum);
    k_gather<<<N_NODES / 32, 256, 0, stream>>>(row, bin, bsum, Whb, out);
}

// Round 13
// 196.258 us; speedup vs baseline: 1.1224x; 1.1224x over previous
//
#include <hip/hip_runtime.h>
#include <math.h>

#define N_NODES 100000
#define N_EDGES 1000000
#define IN_DIM  128
#define OUT_DIM 64
#define NEG     0.2f

#define SCAN_BLOCKS 391   // ceil(100000/256)
#define FILL_BLOCKS 977   // ceil(1000000/1024): 4 edges/thread

// histogram decomposition: 80 edge-groups x 4 node-chunks
#define G_GROUPS 80
#define EPG      (N_EDGES / G_GROUPS)   // 12500 edges per group (even)
#define NI2      (EPG / 2)              // 6250 int2 per group
#define CHUNK_N  25000                  // nodes per chunk (50 KB packed u16)
#define HIST_BLOCKS (G_GROUPS * 4)      // 320

// ---------------------------------------------------------------------------
// K1: Wh = h@W^T + b via bf16x2 split-precision MFMA. Wh stored as RNE bf16
// (Whb). Scores fp32. (unchanged — R5-proven)
// ---------------------------------------------------------------------------
typedef __attribute__((ext_vector_type(8))) short short8;   // 8 bf16 = 4 VGPR
typedef __attribute__((ext_vector_type(4))) float f32x4;

#define MFMA(A, B, C) __builtin_amdgcn_mfma_f32_16x16x32_bf16(A, B, C, 0, 0, 0)

union U16 { unsigned u[4]; short8 s; };

__device__ __forceinline__ void split8(const float* x, short8& hi, short8& lo) {
    U16 H, L;
#pragma unroll
    for (int i = 0; i < 4; ++i) {
        float a = x[2 * i], b = x[2 * i + 1];
        unsigned ua = __float_as_uint(a), ub = __float_as_uint(b);
        unsigned ha = ua & 0xffff0000u, hb = ub & 0xffff0000u;
        H.u[i] = (ua >> 16) | hb;
        float la = a - __uint_as_float(ha);     // exact (low mantissa bits)
        float lb = b - __uint_as_float(hb);
        L.u[i] = (__float_as_uint(la) >> 16) | (__float_as_uint(lb) & 0xffff0000u);
    }
    hi = H.s; lo = L.s;
}

// pack two fp32 -> one u32 of two RNE bf16
__device__ __forceinline__ unsigned pk2(float a, float b) {
    unsigned ua = __float_as_uint(a); ua = (ua + 0x7fffu + ((ua >> 16) & 1u)) >> 16;
    unsigned ub = __float_as_uint(b); ub = (ub + 0x7fffu + ((ub >> 16) & 1u)) >> 16;
    return ua | (ub << 16);
}

__global__ __launch_bounds__(256, 3) void k1_mfma(
    const float* __restrict__ h, const float* __restrict__ W,
    const float* __restrict__ Wb, const float* __restrict__ aw,
    unsigned short* __restrict__ Whb, float* __restrict__ s_src,
    float* __restrict__ s_tgt)
{
    __shared__ float4 smem4[2176];     // 34816 B: W frags, then tr[128][68]
    unsigned short* wfh = (unsigned short*)smem4;
    unsigned short* wfl = wfh + 8192;

    const int tid  = threadIdx.x;
    const int lane = tid & 63, w = tid >> 6;
    const int c = lane & 15, g = lane >> 4;
    const int n0 = blockIdx.x * 128;

#pragma unroll
    for (int it = 0; it < 4; ++it) {
        int U = tid + 256 * it;                 // 0..1023
        int pos = U >> 6, l = U & 63;
        int nb = pos >> 2, ks = pos & 3;
        int r  = 16 * nb + (l & 15);
        int k0 = 32 * ks + 8 * (l >> 4);
        float a[8];
        *(float4*)&a[0] = *(const float4*)(W + r * IN_DIM + k0);
        *(float4*)&a[4] = *(const float4*)(W + r * IN_DIM + k0 + 4);
        short8 hi, lo; split8(a, hi, lo);
        *(short8*)(wfh + (size_t)U * 8) = hi;   // stride-1 b128 writes
        *(short8*)(wfl + (size_t)U * 8) = lo;
    }
    __syncthreads();

    const int na0 = n0 + 32 * w + c;
    const float* hp0 = h + (size_t)min(na0, N_NODES - 1) * IN_DIM + 8 * g;
    const float* hp1 = h + (size_t)min(na0 + 16, N_NODES - 1) * IN_DIM + 8 * g;

    f32x4 acc[2][4];
    {
        f32x4 z = {0.f, 0.f, 0.f, 0.f};
#pragma unroll
        for (int m = 0; m < 2; ++m)
#pragma unroll
            for (int nb = 0; nb < 4; ++nb) acc[m][nb] = z;
    }

#pragma unroll 2
    for (int ks = 0; ks < 4; ++ks) {
        short8 bh[4], bl[4];
#pragma unroll
        for (int nb = 0; nb < 4; ++nb) {
            int u = ((nb * 4 + ks) * 64 + lane) * 8;
            bh[nb] = *(const short8*)(wfh + u);
            bl[nb] = *(const short8*)(wfl + u);
        }
        float am[8];
        short8 ah, al;
        *(float4*)&am[0] = *(const float4*)(hp0 + 32 * ks);
        *(float4*)&am[4] = *(const float4*)(hp0 + 32 * ks + 4);
        split8(am, ah, al);
#pragma unroll
        for (int nb = 0; nb < 4; ++nb) {
            acc[0][nb] = MFMA(ah, bh[nb], acc[0][nb]);
            acc[0][nb] = MFMA(ah, bl[nb], acc[0][nb]);
            acc[0][nb] = MFMA(al, bh[nb], acc[0][nb]);
        }
        *(float4*)&am[0] = *(const float4*)(hp1 + 32 * ks);
        *(float4*)&am[4] = *(const float4*)(hp1 + 32 * ks + 4);
        split8(am, ah, al);
#pragma unroll
        for (int nb = 0; nb < 4; ++nb) {
            acc[1][nb] = MFMA(ah, bh[nb], acc[1][nb]);
            acc[1][nb] = MFMA(ah, bl[nb], acc[1][nb]);
            acc[1][nb] = MFMA(al, bh[nb], acc[1][nb]);
        }
    }

    // epilogue: bias + score dot-products (fp32, pre-cast).
    // D-frag: lane holds Wh[32w + 16m + 4g + r][16nb + c], r = 0..3.
    float wb[4], w1[4], w2[4];
#pragma unroll
    for (int nb = 0; nb < 4; ++nb) {
        wb[nb] = Wb[16 * nb + c];
        w1[nb] = aw[16 * nb + c];
        w2[nb] = aw[OUT_DIM + 16 * nb + c];
    }
#pragma unroll
    for (int m = 0; m < 2; ++m)
#pragma unroll
        for (int r = 0; r < 4; ++r) {
            float s1 = 0.f, s2 = 0.f;
#pragma unroll
            for (int nb = 0; nb < 4; ++nb) {
                float v = acc[m][nb][r] + wb[nb];
                acc[m][nb][r] = v;
                s1 = fmaf(v, w1[nb], s1);
                s2 = fmaf(v, w2[nb], s2);
            }
#pragma unroll
            for (int mk = 1; mk < 16; mk <<= 1) {
                s1 += __shfl_xor(s1, mk);
                s2 += __shfl_xor(s2, mk);
            }
            if (c == 0) {
                int node = n0 + 32 * w + 16 * m + 4 * g + r;
                if (node < N_NODES) { s_src[node] = s1; s_tgt[node] = s2; }
            }
        }

    __syncthreads();                 // all LDS W reads done; reuse as tr
    float* tr = (float*)smem4;       // tr[128][68]
#pragma unroll
    for (int m = 0; m < 2; ++m)
#pragma unroll
        for (int nb = 0; nb < 4; ++nb)
#pragma unroll
            for (int r = 0; r < 4; ++r)
                tr[(32 * w + 16 * m + 4 * g + r) * 68 + 16 * nb + c] = acc[m][nb][r];
    __syncthreads();

    // coalesced Whb store: 1024 uint4 (8 bf16 each), 4 per thread
#pragma unroll
    for (int j = 0; j < 4; ++j) {
        int idx = tid + 256 * j;              // 0..1023
        int nloc = idx >> 3, q = idx & 7;
        int node = n0 + nloc;
        if (node < N_NODES) {
            const float* r8 = &tr[nloc * 68 + q * 8];
            uint4 u;
            u.x = pk2(r8[0], r8[1]); u.y = pk2(r8[2], r8[3]);
            u.z = pk2(r8[4], r8[5]); u.w = pk2(r8[6], r8[7]);
            ((uint4*)Whb)[(size_t)node * 8 + q] = u;
        }
    }
}

// ---------------------------------------------------------------------------
// k_hist: packed-u16 LDS counters, 320 blocks, 8-deep load batch.
// (unchanged — R10-proven)
// ---------------------------------------------------------------------------
__global__ __launch_bounds__(256) void k_hist(
    const int* __restrict__ ei, unsigned char* __restrict__ deg_g8,
    unsigned* __restrict__ rank)
{
    __shared__ unsigned cnt[CHUNK_N / 2];      // 50 KB, two u16 per word
    const int g  = blockIdx.x >> 2;
    const int c0 = (blockIdx.x & 3) * CHUNK_N;
    const int tid = threadIdx.x;

    for (int i = tid; i < CHUNK_N / 2; i += 256) cnt[i] = 0u;
    __syncthreads();

    const int ebase = g * EPG;
    const int2* tp2 = (const int2*)(ei + N_EDGES + ebase);
    for (int b = 0; b < 32; b += 8) {
        int2 tv[8];
#pragma unroll
        for (int k = 0; k < 8; ++k) {
            int idx = tid + (b + k) * 256;
            tv[k] = (idx < NI2) ? tp2[idx] : make_int2(-0x40000000, -0x40000000);
        }
#pragma unroll
        for (int k = 0; k < 8; ++k) {
            int idx = tid + (b + k) * 256;
            int e0 = ebase + 2 * idx;
            unsigned u0 = (unsigned)(tv[k].x - c0), u1 = (unsigned)(tv[k].y - c0);
            if (u0 < CHUNK_N) {
                unsigned sh = (u0 & 1u) * 16u;
                unsigned old = atomicAdd(&cnt[u0 >> 1], 1u << sh);
                rank[e0] = (old >> sh) & 0xffffu;
            }
            if (u1 < CHUNK_N) {
                unsigned sh = (u1 & 1u) * 16u;
                unsigned old = atomicAdd(&cnt[u1 >> 1], 1u << sh);
                rank[e0 + 1] = (old >> sh) & 0xffffu;
            }
        }
    }
    __syncthreads();

    unsigned* dg = (unsigned*)(deg_g8 + (size_t)g * N_NODES + c0);
    for (int i = tid; i < CHUNK_N / 4; i += 256) {
        unsigned w0 = cnt[2 * i], w1 = cnt[2 * i + 1];
        dg[i] = (w0 & 0xffu) | (((w0 >> 16) & 0xffu) << 8) |
                ((w1 & 0xffu) << 16) | (((w1 >> 16) & 0xffu) << 24);
    }
}

// ---------------------------------------------------------------------------
// k_scanA: psum[b] = total degree of node block b. (unchanged)
// ---------------------------------------------------------------------------
__global__ __launch_bounds__(256) void k_scanA(
    const unsigned char* __restrict__ deg_g8, unsigned* __restrict__ psum)
{
    const int i = blockIdx.x * 256 + threadIdx.x;
    unsigned v = 0;
    if (i < N_NODES) {
#pragma unroll
        for (int x = 0; x < G_GROUPS; ++x)
            v += deg_g8[(size_t)x * N_NODES + i];
    }
#pragma unroll
    for (int off = 32; off; off >>= 1) v += __shfl_xor(v, off);
    __shared__ unsigned us[4];
    if ((threadIdx.x & 63) == 0) us[threadIdx.x >> 6] = v;
    __syncthreads();
    if (threadIdx.x == 0) psum[blockIdx.x] = us[0] + us[1] + us[2] + us[3];
}

// ---------------------------------------------------------------------------
// k_scan3: row[] (CSR) + per-group relative u8 offsets roff[g][t].
// (unchanged — R11-proven)
// ---------------------------------------------------------------------------
__global__ __launch_bounds__(256) void k_scan3(
    const unsigned char* __restrict__ deg_g8, const unsigned* __restrict__ psum,
    unsigned* __restrict__ row, unsigned char* __restrict__ roff)
{
    __shared__ unsigned sc[256];
    __shared__ unsigned ps[4];
    const int t = threadIdx.x;
    const int i = blockIdx.x * 256 + t;

    // block base = sum of psum[0 .. blockIdx.x-1]
    unsigned pv = 0;
    if (t < blockIdx.x) pv = psum[t];
    if (t + 256 < blockIdx.x) pv += psum[t + 256];
#pragma unroll
    for (int off = 32; off; off >>= 1) pv += __shfl_xor(pv, off);
    if ((t & 63) == 0) ps[t >> 6] = pv;

    unsigned tot = 0;
    if (i < N_NODES) {
#pragma unroll
        for (int x = 0; x < G_GROUPS; ++x)
            tot += deg_g8[(size_t)x * N_NODES + i];
    }
    sc[t] = tot;
    __syncthreads();
    for (int off = 1; off < 256; off <<= 1) {
        unsigned u = (t >= off) ? sc[t - off] : 0u;
        __syncthreads();
        sc[t] += u;
        __syncthreads();
    }
    const unsigned bb = ps[0] + ps[1] + ps[2] + ps[3];
    if (i < N_NODES) {
        row[i] = bb + sc[t] - tot;          // exclusive
        unsigned run = 0;                    // relative prefix, fits u8
#pragma unroll
        for (int x = 0; x < G_GROUPS; ++x) {
            roff[(size_t)x * N_NODES + i] = (unsigned char)run;
            run += deg_g8[(size_t)x * N_NODES + i];
        }
    }
    if (i == 0) row[N_NODES] = N_EDGES;
}

// ---------------------------------------------------------------------------
// k_fill: 4 edges/thread, batched gather chains. (unchanged — R11-proven)
// ---------------------------------------------------------------------------
__global__ __launch_bounds__(256) void k_fill(
    const int* __restrict__ ei, const float* __restrict__ s_src,
    const float* __restrict__ s_tgt, const float* __restrict__ ab,
    const unsigned* __restrict__ rank, const unsigned* __restrict__ row,
    const unsigned char* __restrict__ roff,
    int2* __restrict__ bin, float* __restrict__ bsum)
{
    const float ab0 = ab[0];
    const int base = blockIdx.x * 1024 + threadIdx.x;

    int  s[4], t[4], ee[4];
    bool ok[4];
#pragma unroll
    for (int k = 0; k < 4; ++k) {
        int e = base + 256 * k;
        ok[k] = e < N_EDGES;
        ee[k] = ok[k] ? e : 0;
        s[k] = ei[ee[k]];
        t[k] = ei[N_EDGES + ee[k]];
    }

    float xs[4], xt[4];
    unsigned ps_[4], rk[4];
#pragma unroll
    for (int k = 0; k < 4; ++k) {
        xs[k] = s_src[s[k]];
        xt[k] = s_tgt[t[k]];
        int g = ee[k] / EPG;                  // const div -> magic multiply
        ps_[k] = row[t[k]] + roff[(size_t)g * N_NODES + t[k]];
        rk[k] = rank[ee[k]];
    }

    float lsum = 0.f;
#pragma unroll
    for (int k = 0; k < 4; ++k) {
        float x = xs[k] + xt[k] + ab0;
        float l = x > 0.f ? x : NEG * x;
        float ex = __expf(l);
        if (ok[k]) {
            lsum += ex;
            bin[ps_[k] + rk[k]] = make_int2(s[k], __float_as_int(ex));
        }
    }
#pragma unroll
    for (int off = 32; off; off >>= 1) lsum += __shfl_xor(lsum, off);
    __shared__ float ssum[4];
    if ((threadIdx.x & 63) == 0) ssum[threadIdx.x >> 6] = lsum;
    __syncthreads();
    if (threadIdx.x == 0)
        bsum[blockIdx.x] = ssum[0] + ssum[1] + ssum[2] + ssum[3];
}

// ---------------------------------------------------------------------------
// k_gsum: reduce bsum[FILL_BLOCKS] -> gsum.
// ---------------------------------------------------------------------------
__global__ __launch_bounds__(512) void k_gsum(
    const float* __restrict__ bsum, float* __restrict__ gsum)
{
    __shared__ float sf[8];
    const int t = threadIdx.x;
    float s = 0.f;
    for (int i = t; i < FILL_BLOCKS; i += 512) s += bsum[i];
#pragma unroll
    for (int off = 32; off; off >>= 1) s += __shfl_xor(s, off);
    if ((t & 63) == 0) sf[t >> 6] = s;
    __syncthreads();
    if (t == 0) {
        float tot = 0.f;
#pragma unroll
        for (int i = 0; i < 8; ++i) tot += sf[i];
        gsum[0] = tot;
    }
}

// ---------------------------------------------------------------------------
// K4 (4-node quad gather): wave handles 4 nodes with 4 independent
// {bounds, bin, acc} states interleaved -> 16 edges in flight per wave.
// (reverted to R11-measured version: R12's 8-node variant regressed
// 20 -> 54us — register-state overflow (VGPR 44 < ~60 live) + max-of-8
// padding waste. 4 nodes/wave is the sweet spot on this degree
// distribution.)
// ---------------------------------------------------------------------------
__global__ __launch_bounds__(256) void k_gather(
    const unsigned* __restrict__ row, const int2* __restrict__ bin,
    const float* __restrict__ gsum, const unsigned short* __restrict__ Whb,
    float* __restrict__ out)
{
    const int lane = threadIdx.x & 63;
    const int tb = blockIdx.x * 16 + (threadIdx.x >> 6) * 4;  // 4 nodes/wave
    const int q = lane >> 4, sub = lane & 15;

    const unsigned r0 = row[tb],     r1 = row[tb + 1], r2 = row[tb + 2];
    const unsigned r3 = row[tb + 3], r4 = row[tb + 4];
    unsigned base0 = r0, base1 = r1, base2 = r2, base3 = r3;

    f32x4 a0 = {0.f, 0.f, 0.f, 0.f}, a1 = a0, a2 = a0, a3 = a0;

    while (base0 < r1 || base1 < r2 || base2 < r3 || base3 < r4) {
        const int c0 = base0 < r1 ? (int)min(64u, r1 - base0) : 0;
        const int c1 = base1 < r2 ? (int)min(64u, r2 - base1) : 0;
        const int c2 = base2 < r3 ? (int)min(64u, r3 - base2) : 0;
        const int c3 = base3 < r4 ? (int)min(64u, r4 - base3) : 0;
        int2 p0 = make_int2(0, 0), p1 = p0, p2 = p0, p3 = p0;
        if (lane < c0) p0 = bin[base0 + lane];
        if (lane < c1) p1 = bin[base1 + lane];
        if (lane < c2) p2 = bin[base2 + lane];
        if (lane < c3) p3 = bin[base3 + lane];
        const int cm = max(max(c0, c1), max(c2, c3));
        for (int j = 0; j < cm; j += 4) {
            // 4 independent chains; padded lanes hold (0, +0.0f)
            int   s0 = __shfl(p0.x, j + q);
            float w0 = __int_as_float(__shfl(p0.y, j + q));
            int   s1 = __shfl(p1.x, j + q);
            float w1 = __int_as_float(__shfl(p1.y, j + q));
            int   s2 = __shfl(p2.x, j + q);
            float w2 = __int_as_float(__shfl(p2.y, j + q));
            int   s3 = __shfl(p3.x, j + q);
            float w3 = __int_as_float(__shfl(p3.y, j + q));
            ushort4 v0 = *(const ushort4*)(Whb + (size_t)s0 * OUT_DIM + 4 * sub);
            ushort4 v1 = *(const ushort4*)(Whb + (size_t)s1 * OUT_DIM + 4 * sub);
            ushort4 v2 = *(const ushort4*)(Whb + (size_t)s2 * OUT_DIM + 4 * sub);
            ushort4 v3 = *(const ushort4*)(Whb + (size_t)s3 * OUT_DIM + 4 * sub);
            a0.x = fmaf(w0, __uint_as_float((unsigned)v0.x << 16), a0.x);
            a0.y = fmaf(w0, __uint_as_float((unsigned)v0.y << 16), a0.y);
            a0.z = fmaf(w0, __uint_as_float((unsigned)v0.z << 16), a0.z);
            a0.w = fmaf(w0, __uint_as_float((unsigned)v0.w << 16), a0.w);
            a1.x = fmaf(w1, __uint_as_float((unsigned)v1.x << 16), a1.x);
            a1.y = fmaf(w1, __uint_as_float((unsigned)v1.y << 16), a1.y);
            a1.z = fmaf(w1, __uint_as_float((unsigned)v1.z << 16), a1.z);
            a1.w = fmaf(w1, __uint_as_float((unsigned)v1.w << 16), a1.w);
            a2.x = fmaf(w2, __uint_as_float((unsigned)v2.x << 16), a2.x);
            a2.y = fmaf(w2, __uint_as_float((unsigned)v2.y << 16), a2.y);
            a2.z = fmaf(w2, __uint_as_float((unsigned)v2.z << 16), a2.z);
            a2.w = fmaf(w2, __uint_as_float((unsigned)v2.w << 16), a2.w);
            a3.x = fmaf(w3, __uint_as_float((unsigned)v3.x << 16), a3.x);
            a3.y = fmaf(w3, __uint_as_float((unsigned)v3.y << 16), a3.y);
            a3.z = fmaf(w3, __uint_as_float((unsigned)v3.z << 16), a3.z);
            a3.w = fmaf(w3, __uint_as_float((unsigned)v3.w << 16), a3.w);
        }
        base0 += 64; base1 += 64; base2 += 64; base3 += 64;
    }

    const float inv = 1.0f / gsum[0];
#pragma unroll
    for (int n = 0; n < 4; ++n) {
        f32x4 a = (n == 0) ? a0 : (n == 1) ? a1 : (n == 2) ? a2 : a3;
        a.x += __shfl_xor(a.x, 16); a.x += __shfl_xor(a.x, 32);
        a.y += __shfl_xor(a.y, 16); a.y += __shfl_xor(a.y, 32);
        a.z += __shfl_xor(a.z, 16); a.z += __shfl_xor(a.z, 32);
        a.w += __shfl_xor(a.w, 16); a.w += __shfl_xor(a.w, 32);
        float r = (q == 0) ? a.x : (q == 1) ? a.y : (q == 2) ? a.z : a.w;
        r *= inv;
        r = r > 0.f ? r : NEG * r;
        out[(size_t)(tb + n) * OUT_DIM + 4 * sub + q] = r;
    }
}

extern "C" void kernel_launch(void* const* d_in, const int* in_sizes, int n_in,
                              void* d_out, int out_size, void* d_ws, size_t ws_size,
                              hipStream_t stream)
{
    const float* h  = (const float*)d_in[0];
    const float* W  = (const float*)d_in[1];
    const float* Wb = (const float*)d_in[2];
    const float* aw = (const float*)d_in[3];
    const float* ab = (const float*)d_in[4];
    const int*   ei = (const int*)d_in[5];

    // ws: Whb[64N] u16 (12.8MB) | bin[E] int2 (8-aligned) | s_src[N] f32 |
    //     s_tgt[N] f32 | deg_g8[80N] u8 | row[N+1] u32 | roff[80N] u8 |
    //     psum[512] u32 | rank[E] u32 | bsum[1024] f32 | gsum   (~43 MB)
    unsigned short* Whb = (unsigned short*)d_ws;
    int2*  bin   = (int2*)(Whb + (size_t)N_NODES * OUT_DIM);   // 12.8M % 8 == 0
    float* s_src = (float*)(bin + N_EDGES);
    float* s_tgt = s_src + N_NODES;
    unsigned char* deg_g8 = (unsigned char*)(s_tgt + N_NODES);
    unsigned* row  = (unsigned*)(deg_g8 + (size_t)G_GROUPS * N_NODES);
    unsigned char* roff = (unsigned char*)(row + N_NODES + 1);
    unsigned* psum = (unsigned*)(roff + (size_t)G_GROUPS * N_NODES);
    unsigned* rank = psum + 512;
    float* bsum = (float*)(rank + N_EDGES);
    float* gsum = bsum + 1024;

    float* out = (float*)d_out;

    k_hist<<<HIST_BLOCKS, 256, 0, stream>>>(ei, deg_g8, rank);
    k1_mfma<<<(N_NODES + 127) / 128, 256, 0, stream>>>(h, W, Wb, aw, Whb,
                                                       s_src, s_tgt);
    k_scanA<<<SCAN_BLOCKS, 256, 0, stream>>>(deg_g8, psum);
    k_scan3<<<SCAN_BLOCKS, 256, 0, stream>>>(deg_g8, psum, row, roff);
    k_fill<<<FILL_BLOCKS, 256, 0, stream>>>(ei, s_src, s_tgt, ab, rank,
                                            row, roff, bin, bsum);
    k_gsum<<<1, 512, 0, stream>>>(bsum, gsum);
    k_gather<<<(N_NODES + 15) / 16, 256, 0, stream>>>(row, bin, gsum, Whb, out);
}